// Round 8
// baseline (52.676 us; speedup 1.0000x reference)
//
#include <hip/hip_runtime.h>

#define NN 4096
#define EE 65536
#define DD 128

// ---------------- zero degree arrays (indeg+outdeg contiguous) ----------------
__global__ void k_zero(int* __restrict__ p) {
    p[blockIdx.x * 256 + threadIdx.x] = 0;   // 32 x 256 = 8192
}

// ---------------- degree count: 2 edges/thread ----------------
__global__ void k_deg(const int* __restrict__ ei, int* __restrict__ indeg,
                      int* __restrict__ outdeg) {
    int t = blockIdx.x * 256 + threadIdx.x;
    int2 s = *(const int2*)&ei[2 * t];
    int2 d = *(const int2*)&ei[EE + 2 * t];
    atomicAdd(&outdeg[s.x], 1);
    atomicAdd(&outdeg[s.y], 1);
    atomicAdd(&indeg[d.x], 1);
    atomicAdd(&indeg[d.y], 1);
}

// GEMM core: thread (c2, np, kh) accumulates 2 nodes x 2 cols over its K-half.
// One float2 W load feeds 4 FMAs; y rows broadcast from LDS.
__device__ __forceinline__ void gemm22(const float* __restrict__ W, int ks, int nk4,
                                       int c2, const float* __restrict__ y0,
                                       const float* __restrict__ y1,
                                       float2& a0, float2& a1) {
#pragma unroll 4
    for (int k4 = 0; k4 < nk4; ++k4) {
        float4 v0 = *(const float4*)&y0[ks + k4 * 4];
        float4 v1 = *(const float4*)&y1[ks + k4 * 4];
#pragma unroll
        for (int kk = 0; kk < 4; ++kk) {
            float2 w = *(const float2*)&W[(size_t)(ks + k4 * 4 + kk) * DD + c2 * 2];
            float e0 = kk == 0 ? v0.x : kk == 1 ? v0.y : kk == 2 ? v0.z : v0.w;
            float e1 = kk == 0 ? v1.x : kk == 1 ? v1.y : kk == 2 ? v1.z : v1.w;
            a0.x += e0 * w.x; a0.y += e0 * w.y;
            a1.x += e1 * w.x; a1.y += e1 * w.y;
        }
    }
}

// ---------------- h0 = x@W_in + b_in + z_in[indeg] + z_out[outdeg] ----------------
// 1024 blocks x 256 thr; 4 nodes/block; thread = (c2 0..63, np 0..1, kh 0..1).
__global__ __launch_bounds__(256) void k_h0(
    const float* __restrict__ x, const float* __restrict__ W_in,
    const float* __restrict__ b_in, const float* __restrict__ z_in,
    const float* __restrict__ z_out, const int* __restrict__ indeg,
    const int* __restrict__ outdeg, float* __restrict__ h) {
    __shared__ float xs[4][64];
    __shared__ float part[4][DD];
    const int tid = threadIdx.x, c2 = tid & 63, np = (tid >> 6) & 1, kh = tid >> 7;
    const int n0 = blockIdx.x * 4;

    xs[tid >> 6][tid & 63] = x[(size_t)(n0 + (tid >> 6)) * 64 + (tid & 63)];
    __syncthreads();

    float2 a0 = {0.f, 0.f}, a1 = {0.f, 0.f};
    gemm22(W_in, kh * 32, 8, c2, &xs[np * 2][0], &xs[np * 2 + 1][0], a0, a1);
    if (kh) {
        *(float2*)&part[np * 2][c2 * 2] = a0;
        *(float2*)&part[np * 2 + 1][c2 * 2] = a1;
    }
    __syncthreads();
    if (!kh) {
        const int c = c2 * 2;
        float2 bi = *(const float2*)&b_in[c];
#pragma unroll
        for (int i = 0; i < 2; ++i) {
            int n = np * 2 + i, gn = n0 + n;
            int di = min(indeg[gn], 63), dq = min(outdeg[gn], 63);
            float2 p = *(float2*)&part[n][c];
            float2 zi = *(const float2*)&z_in[(size_t)di * DD + c];
            float2 zo = *(const float2*)&z_out[(size_t)dq * DD + c];
            float2 acc = (i == 0) ? a0 : a1;
            *(float2*)&h[(size_t)gn * DD + c] = make_float2(
                acc.x + p.x + bi.x + zi.x + zo.x, acc.y + p.y + bi.y + zi.y + zo.y);
        }
    }
}

// ---------------- layer: xp = h + bo; h = LN(xp)@Wff + bff + xp ----------------
// Attention output is exactly zero (multiplicative -1e6 mask => softmax max is a
// huge positive cross-graph logit => within-graph exp underflows to 0; the zero
// mask then kills the cross-graph cols), so only this path survives.
__global__ __launch_bounds__(256) void k_layer(
    float* __restrict__ h, const float* __restrict__ bo, const float* __restrict__ g,
    const float* __restrict__ bb, const float* __restrict__ Wff,
    const float* __restrict__ bff) {
    __shared__ float ybuf[4][DD];
    __shared__ float xps[4][DD];
    __shared__ float part[4][DD];
    const int tid = threadIdx.x, c2 = tid & 63, np = (tid >> 6) & 1, kh = tid >> 7;
    const int n0 = blockIdx.x * 4;

    // LN: wave w = node w; lane j handles cols j, j+64
    {
        int n = tid >> 6, j = tid & 63;
        float xpA = h[(size_t)(n0 + n) * DD + j] + bo[j];
        float xpB = h[(size_t)(n0 + n) * DD + j + 64] + bo[j + 64];
        float s = xpA + xpB;
        s += __shfl_xor(s, 32); s += __shfl_xor(s, 16); s += __shfl_xor(s, 8);
        s += __shfl_xor(s, 4);  s += __shfl_xor(s, 2);  s += __shfl_xor(s, 1);
        float mu = s * (1.f / 128.f);
        float cA = xpA - mu, cB = xpB - mu;
        float v = cA * cA + cB * cB;
        v += __shfl_xor(v, 32); v += __shfl_xor(v, 16); v += __shfl_xor(v, 8);
        v += __shfl_xor(v, 4);  v += __shfl_xor(v, 2);  v += __shfl_xor(v, 1);
        float r = rsqrtf(v * (1.f / 128.f) + 1e-5f);
        ybuf[n][j] = cA * r * g[j] + bb[j];
        ybuf[n][j + 64] = cB * r * g[j + 64] + bb[j + 64];
        xps[n][j] = xpA;
        xps[n][j + 64] = xpB;
    }
    __syncthreads();

    float2 a0 = {0.f, 0.f}, a1 = {0.f, 0.f};
    gemm22(Wff, kh * 64, 16, c2, &ybuf[np * 2][0], &ybuf[np * 2 + 1][0], a0, a1);
    if (kh) {
        *(float2*)&part[np * 2][c2 * 2] = a0;
        *(float2*)&part[np * 2 + 1][c2 * 2] = a1;
    }
    __syncthreads();
    if (!kh) {
        const int c = c2 * 2;
        float2 bf = *(const float2*)&bff[c];
#pragma unroll
        for (int i = 0; i < 2; ++i) {
            int n = np * 2 + i, gn = n0 + n;
            float2 p = *(float2*)&part[n][c];
            float2 xp = *(float2*)&xps[n][c];
            float2 acc = (i == 0) ? a0 : a1;
            *(float2*)&h[(size_t)gn * DD + c] = make_float2(
                acc.x + p.x + bf.x + xp.x, acc.y + p.y + bf.y + xp.y);
        }
    }
}

// ---------------- out = h @ W_out + b_out ----------------
__global__ __launch_bounds__(256) void k_out(
    const float* __restrict__ h, const float* __restrict__ Wo,
    const float* __restrict__ bv, float* __restrict__ out) {
    __shared__ float ybuf[4][DD];
    __shared__ float part[4][DD];
    const int tid = threadIdx.x, c2 = tid & 63, np = (tid >> 6) & 1, kh = tid >> 7;
    const int n0 = blockIdx.x * 4;

#pragma unroll
    for (int p = 0; p < 2; ++p) {
        int idx = tid + p * 256;
        ybuf[idx >> 7][idx & 127] = h[(size_t)n0 * DD + idx];
    }
    __syncthreads();

    float2 a0 = {0.f, 0.f}, a1 = {0.f, 0.f};
    gemm22(Wo, kh * 64, 16, c2, &ybuf[np * 2][0], &ybuf[np * 2 + 1][0], a0, a1);
    if (kh) {
        *(float2*)&part[np * 2][c2 * 2] = a0;
        *(float2*)&part[np * 2 + 1][c2 * 2] = a1;
    }
    __syncthreads();
    if (!kh) {
        const int c = c2 * 2;
        float2 b = *(const float2*)&bv[c];
#pragma unroll
        for (int i = 0; i < 2; ++i) {
            int n = np * 2 + i, gn = n0 + n;
            float2 p = *(float2*)&part[n][c];
            float2 acc = (i == 0) ? a0 : a1;
            *(float2*)&out[(size_t)gn * DD + c] =
                make_float2(acc.x + p.x + b.x, acc.y + p.y + b.y);
        }
    }
}

extern "C" void kernel_launch(void* const* d_in, const int* in_sizes, int n_in,
                              void* d_out, int out_size, void* d_ws, size_t ws_size,
                              hipStream_t stream) {
    // inputs: 0 x, 1 edge_index, 2 ptr, 3 dist, 4 W_in, 5 b_in, 6 z_in, 7 z_out,
    // 8 b_spat, 9 Wq, 10 bq, 11 Wk, 12 bk, 13 Wv, 14 bv, 15 Wo, 16 bo,
    // 17 ln1_g, 18 ln1_b, 19 ln2_g, 20 ln2_b, 21 Wff, 22 bff, 23 W_out, 24 b_out
    const float* x = (const float*)d_in[0];
    const int* ei = (const int*)d_in[1];
    const float* W_in = (const float*)d_in[4];
    const float* b_in = (const float*)d_in[5];
    const float* z_in = (const float*)d_in[6];
    const float* z_out = (const float*)d_in[7];
    const float* bo = (const float*)d_in[16];
    const float* ln2_g = (const float*)d_in[19];
    const float* ln2_b = (const float*)d_in[20];
    const float* Wff = (const float*)d_in[21];
    const float* bff = (const float*)d_in[22];
    const float* W_out = (const float*)d_in[23];
    const float* b_out = (const float*)d_in[24];
    float* out = (float*)d_out;

    int* indeg = (int*)d_ws;
    int* outdeg = indeg + NN;
    float* h = (float*)((char*)d_ws + 2 * NN * sizeof(int));

    k_zero<<<2 * NN / 256, 256, 0, stream>>>(indeg);
    k_deg<<<EE / (2 * 256), 256, 0, stream>>>(ei, indeg, outdeg);
    k_h0<<<NN / 4, 256, 0, stream>>>(x, W_in, b_in, z_in, z_out, indeg, outdeg, h);
    k_layer<<<NN / 4, 256, 0, stream>>>(h, bo, ln2_g, ln2_b, Wff, bff);
    k_layer<<<NN / 4, 256, 0, stream>>>(h, bo + DD, ln2_g + DD, ln2_b + DD,
                                        Wff + DD * DD, bff + DD);
    k_out<<<NN / 4, 256, 0, stream>>>(h, W_out, b_out, out);
}

// Round 9
// 27.976 us; speedup vs baseline: 1.8829x; 1.8829x over previous
//
#include <hip/hip_runtime.h>

#define NN 4096
#define EE 65536
#define DD 128

// acc[i] += y[ng*8+i] @ W over this thread's K-slice; one W dword -> 8 FMAs.
__device__ __forceinline__ void gemmq(const float* __restrict__ W, int kstart,
                                      int nk4, int c, const float* __restrict__ y,
                                      int ystr, float acc[8]) {
#pragma unroll 4
    for (int k4 = 0; k4 < nk4; ++k4) {
        int k = kstart + k4 * 4;
        float4 yv[8];
#pragma unroll
        for (int i = 0; i < 8; ++i)
            yv[i] = *(const float4*)&y[i * ystr + k];   // LDS broadcast (uniform addr)
#pragma unroll
        for (int kk = 0; kk < 4; ++kk) {
            float w = W[(size_t)(k + kk) * DD + c];     // L1/L2, 8-way reuse
#pragma unroll
            for (int i = 0; i < 8; ++i) {
                float e = kk == 0 ? yv[i].x : kk == 1 ? yv[i].y
                        : kk == 2 ? yv[i].z : yv[i].w;
                acc[i] += e * w;
            }
        }
    }
}

// Single kernel: in-block degree scan + fused h0 -> layer0 -> layer1 -> out.
// Attention output is exactly zero (multiplicative -1e6 mask => softmax max is a
// huge positive cross-graph logit => within-graph exp underflows to 0; the zero
// mask then kills the cross-graph cols), so only xp=h+bo and the LN2/FF path survive.
// 256 blocks x 1024 thr; GEMM thread = (c=tid&127, ng=(tid>>7)&1, ks=tid>>8);
// wave-per-node phases: wave n handles node n, lane j -> cols j, j+64.
__global__ __launch_bounds__(1024) void k_one(
    const float* __restrict__ x, const int* __restrict__ ei,
    const float* __restrict__ W_in, const float* __restrict__ b_in,
    const float* __restrict__ z_in, const float* __restrict__ z_out,
    const float* __restrict__ bo_all, const float* __restrict__ g_all,
    const float* __restrict__ b_all, const float* __restrict__ Wff_all,
    const float* __restrict__ bff_all, const float* __restrict__ W_out,
    const float* __restrict__ b_out, float* __restrict__ out) {
    __shared__ float part[4][16][DD];   // 32KB K-split partials
    __shared__ float ybuf[16][DD];      // 8KB  GEMM input (LN out / h)
    __shared__ float xps[16][DD];       // 8KB  residual stash
    __shared__ float xs[16][64];        // 4KB  staged x rows
    __shared__ int cin[16], cout_[16];
    const int tid = threadIdx.x;
    const int n0 = blockIdx.x * 16;
    const int c = tid & 127;
    const int ng = (tid >> 7) & 1;
    const int ks = tid >> 8;            // 0..3
    const int wn = tid >> 6;            // wave = node for fused phases
    const int j = tid & 63;

    // ---- stage x rows + zero LDS degree counters ----
    xs[wn][j] = x[(size_t)(n0 + wn) * 64 + j];
    if (tid < 16) { cin[tid] = 0; cout_[tid] = 0; }
    __syncthreads();

    // ---- degree scan FIRST (loads issue early; L2 latency hides under GEMM) ----
    {
        const int4* s4 = (const int4*)ei;
        const int4* d4 = (const int4*)(ei + EE);
        for (int i = tid; i < EE / 4; i += 1024) {
            int4 s = s4[i];
            if ((unsigned)(s.x - n0) < 16u) atomicAdd(&cout_[s.x - n0], 1);
            if ((unsigned)(s.y - n0) < 16u) atomicAdd(&cout_[s.y - n0], 1);
            if ((unsigned)(s.z - n0) < 16u) atomicAdd(&cout_[s.z - n0], 1);
            if ((unsigned)(s.w - n0) < 16u) atomicAdd(&cout_[s.w - n0], 1);
            int4 d = d4[i];
            if ((unsigned)(d.x - n0) < 16u) atomicAdd(&cin[d.x - n0], 1);
            if ((unsigned)(d.y - n0) < 16u) atomicAdd(&cin[d.y - n0], 1);
            if ((unsigned)(d.z - n0) < 16u) atomicAdd(&cin[d.z - n0], 1);
            if ((unsigned)(d.w - n0) < 16u) atomicAdd(&cin[d.w - n0], 1);
        }
    }

    float acc[8];

    // ---- h0 GEMM (K=64, slice=16) ----
#pragma unroll
    for (int i = 0; i < 8; ++i) acc[i] = 0.f;
    gemmq(W_in, ks * 16, 4, c, &xs[ng * 8][0], 64, acc);
#pragma unroll
    for (int i = 0; i < 8; ++i) part[ks][ng * 8 + i][c] = acc[i];
    __syncthreads();

    // ---- fused: h0-reduce + centrality + LN(layer0) ----
    {
        float vA = part[0][wn][j] + part[1][wn][j] + part[2][wn][j] + part[3][wn][j];
        float vB = part[0][wn][j + 64] + part[1][wn][j + 64]
                 + part[2][wn][j + 64] + part[3][wn][j + 64];
        int di = min(cin[wn], 63), dq = min(cout_[wn], 63);
        float hA = vA + b_in[j] + z_in[(size_t)di * DD + j] + z_out[(size_t)dq * DD + j];
        float hB = vB + b_in[j + 64] + z_in[(size_t)di * DD + j + 64]
                 + z_out[(size_t)dq * DD + j + 64];
        float xpA = hA + bo_all[j], xpB = hB + bo_all[j + 64];
        float s = xpA + xpB;
        s += __shfl_xor(s, 32); s += __shfl_xor(s, 16); s += __shfl_xor(s, 8);
        s += __shfl_xor(s, 4);  s += __shfl_xor(s, 2);  s += __shfl_xor(s, 1);
        float mu = s * (1.f / 128.f);
        float cA = xpA - mu, cB = xpB - mu;
        float v = cA * cA + cB * cB;
        v += __shfl_xor(v, 32); v += __shfl_xor(v, 16); v += __shfl_xor(v, 8);
        v += __shfl_xor(v, 4);  v += __shfl_xor(v, 2);  v += __shfl_xor(v, 1);
        float r = rsqrtf(v * (1.f / 128.f) + 1e-5f);
        ybuf[wn][j] = cA * r * g_all[j] + b_all[j];
        ybuf[wn][j + 64] = cB * r * g_all[j + 64] + b_all[j + 64];
        xps[wn][j] = xpA;
        xps[wn][j + 64] = xpB;
    }
    __syncthreads();

    // ---- FF0 GEMM (K=128, slice=32) ----
#pragma unroll
    for (int i = 0; i < 8; ++i) acc[i] = 0.f;
    gemmq(Wff_all, ks * 32, 8, c, &ybuf[ng * 8][0], DD, acc);
#pragma unroll
    for (int i = 0; i < 8; ++i) part[ks][ng * 8 + i][c] = acc[i];
    __syncthreads();

    // ---- fused: FF0-reduce + residual + LN(layer1) ----
    {
        float vA = part[0][wn][j] + part[1][wn][j] + part[2][wn][j] + part[3][wn][j];
        float vB = part[0][wn][j + 64] + part[1][wn][j + 64]
                 + part[2][wn][j + 64] + part[3][wn][j + 64];
        float hA = vA + bff_all[j] + xps[wn][j];
        float hB = vB + bff_all[j + 64] + xps[wn][j + 64];
        float xpA = hA + bo_all[DD + j], xpB = hB + bo_all[DD + j + 64];
        float s = xpA + xpB;
        s += __shfl_xor(s, 32); s += __shfl_xor(s, 16); s += __shfl_xor(s, 8);
        s += __shfl_xor(s, 4);  s += __shfl_xor(s, 2);  s += __shfl_xor(s, 1);
        float mu = s * (1.f / 128.f);
        float cA = xpA - mu, cB = xpB - mu;
        float v = cA * cA + cB * cB;
        v += __shfl_xor(v, 32); v += __shfl_xor(v, 16); v += __shfl_xor(v, 8);
        v += __shfl_xor(v, 4);  v += __shfl_xor(v, 2);  v += __shfl_xor(v, 1);
        float r = rsqrtf(v * (1.f / 128.f) + 1e-5f);
        ybuf[wn][j] = cA * r * g_all[DD + j] + b_all[DD + j];
        ybuf[wn][j + 64] = cB * r * g_all[DD + j + 64] + b_all[DD + j + 64];
        xps[wn][j] = xpA;
        xps[wn][j + 64] = xpB;
    }
    __syncthreads();

    // ---- FF1 GEMM ----
#pragma unroll
    for (int i = 0; i < 8; ++i) acc[i] = 0.f;
    gemmq(Wff_all + DD * DD, ks * 32, 8, c, &ybuf[ng * 8][0], DD, acc);
#pragma unroll
    for (int i = 0; i < 8; ++i) part[ks][ng * 8 + i][c] = acc[i];
    __syncthreads();

    // ---- fused: FF1-reduce + residual -> h (into ybuf for out-GEMM) ----
    {
        float vA = part[0][wn][j] + part[1][wn][j] + part[2][wn][j] + part[3][wn][j];
        float vB = part[0][wn][j + 64] + part[1][wn][j + 64]
                 + part[2][wn][j + 64] + part[3][wn][j + 64];
        ybuf[wn][j] = vA + bff_all[DD + j] + xps[wn][j];
        ybuf[wn][j + 64] = vB + bff_all[DD + j + 64] + xps[wn][j + 64];
    }
    __syncthreads();

    // ---- out GEMM ----
#pragma unroll
    for (int i = 0; i < 8; ++i) acc[i] = 0.f;
    gemmq(W_out, ks * 32, 8, c, &ybuf[ng * 8][0], DD, acc);
#pragma unroll
    for (int i = 0; i < 8; ++i) part[ks][ng * 8 + i][c] = acc[i];
    __syncthreads();

    // ---- final reduce + b_out + store (coalesced) ----
    {
        float vA = part[0][wn][j] + part[1][wn][j] + part[2][wn][j] + part[3][wn][j];
        float vB = part[0][wn][j + 64] + part[1][wn][j + 64]
                 + part[2][wn][j + 64] + part[3][wn][j + 64];
        out[(size_t)(n0 + wn) * DD + j] = vA + b_out[j];
        out[(size_t)(n0 + wn) * DD + j + 64] = vB + b_out[j + 64];
    }
}

extern "C" void kernel_launch(void* const* d_in, const int* in_sizes, int n_in,
                              void* d_out, int out_size, void* d_ws, size_t ws_size,
                              hipStream_t stream) {
    // inputs: 0 x, 1 edge_index, 2 ptr, 3 dist, 4 W_in, 5 b_in, 6 z_in, 7 z_out,
    // 8 b_spat, 9 Wq, 10 bq, 11 Wk, 12 bk, 13 Wv, 14 bv, 15 Wo, 16 bo,
    // 17 ln1_g, 18 ln1_b, 19 ln2_g, 20 ln2_b, 21 Wff, 22 bff, 23 W_out, 24 b_out
    const float* x = (const float*)d_in[0];
    const int* ei = (const int*)d_in[1];
    const float* W_in = (const float*)d_in[4];
    const float* b_in = (const float*)d_in[5];
    const float* z_in = (const float*)d_in[6];
    const float* z_out = (const float*)d_in[7];
    const float* bo = (const float*)d_in[16];
    const float* ln2_g = (const float*)d_in[19];
    const float* ln2_b = (const float*)d_in[20];
    const float* Wff = (const float*)d_in[21];
    const float* bff = (const float*)d_in[22];
    const float* W_out = (const float*)d_in[23];
    const float* b_out = (const float*)d_in[24];
    float* out = (float*)d_out;

    k_one<<<NN / 16, 1024, 0, stream>>>(x, ei, W_in, b_in, z_in, z_out,
                                        bo, ln2_g, ln2_b, Wff, bff, W_out, b_out, out);
}